// Round 1
// baseline (954.588 us; speedup 1.0000x reference)
//
#include <hip/hip_runtime.h>
#include <hip/hip_bf16.h>

#define HEADS 8
#define D 128
#define PE 64
#define NP 1024         // positions per batch (32*32)
#define NT 8192         // total tokens (8*1024)
#define INV_SQRT_D 0.08838834764831845f

__device__ inline float bf2f(unsigned int u) {
    return __uint_as_float(u << 16);
}
__device__ inline void bf8_to_f(const uint4 u, float* o) {
    o[0] = bf2f(u.x & 0xffffu); o[1] = bf2f(u.x >> 16);
    o[2] = bf2f(u.y & 0xffffu); o[3] = bf2f(u.y >> 16);
    o[4] = bf2f(u.z & 0xffffu); o[5] = bf2f(u.z >> 16);
    o[6] = bf2f(u.w & 0xffffu); o[7] = bf2f(u.w >> 16);
}

// ---------------- K1: LayerNorm ----------------
// one wave per row of 128; 4 rows per block
__global__ __launch_bounds__(256) void k_ln(const float* __restrict__ hs,
    const float* __restrict__ g, const float* __restrict__ b,
    float* __restrict__ xf)
{
    int row  = blockIdx.x * 4 + (threadIdx.x >> 6);
    int lane = threadIdx.x & 63;
    const float* p = hs + (size_t)row * D + lane * 2;
    float2 v = *(const float2*)p;
    float s  = v.x + v.y;
    float s2 = v.x * v.x + v.y * v.y;
    #pragma unroll
    for (int off = 1; off < 64; off <<= 1) {
        s  += __shfl_xor(s, off);
        s2 += __shfl_xor(s2, off);
    }
    float mu  = s * 0.0078125f;
    float var = s2 * 0.0078125f - mu * mu;
    float inv = rsqrtf(var + 1e-5f);
    float2 o;
    o.x = (v.x - mu) * inv * g[lane * 2 + 0] + b[lane * 2 + 0];
    o.y = (v.y - mu) * inv * g[lane * 2 + 1] + b[lane * 2 + 1];
    *(float2*)(xf + (size_t)row * D + lane * 2) = o;
}

// ---------------- K2: Q/K projection ----------------
// out o in [0,2048): o<1024 -> Q (head=o>>7, d=o&127), else K.
// q_bf[(b*8+head)*1024 + pos][d],  pos = I*32+J
// kt_bf[(b*8+head)*1024 + (J*32+I)][d]   (spatial pre-transpose: key kk=(L,K) reads kproj at (K,L))
__global__ __launch_bounds__(256) void k_proj(const float* __restrict__ xf,
    const float* __restrict__ Wq, const float* __restrict__ Wk,
    __hip_bfloat16* __restrict__ q_bf, __hip_bfloat16* __restrict__ kt_bf)
{
    __shared__ __align__(16) float AX[64 * 128];   // [token][k] row-major
    __shared__ __align__(16) float WT[128 * 68];   // [k][o] transposed
    int tid = threadIdx.x;
    int t0 = blockIdx.x * 64;
    int o0 = blockIdx.y * 64;
    #pragma unroll
    for (int it = 0; it < 8; ++it) {
        int s = tid + it * 256;          // 2048 slots: 64 rows x 32 f4
        int r = s >> 5, c4 = s & 31;
        *(float4*)&AX[r * 128 + c4 * 4] =
            *(const float4*)(xf + (size_t)(t0 + r) * 128 + c4 * 4);
    }
    #pragma unroll
    for (int it = 0; it < 8; ++it) {
        int s = tid + it * 256;
        int r = s >> 5, c4 = s & 31;
        int orow = o0 + r;
        const float* Wsrc = (orow < 1024) ? (Wq + (size_t)orow * 128)
                                          : (Wk + (size_t)(orow - 1024) * 128);
        float4 v = *(const float4*)(Wsrc + c4 * 4);
        WT[(c4 * 4 + 0) * 68 + r] = v.x;
        WT[(c4 * 4 + 1) * 68 + r] = v.y;
        WT[(c4 * 4 + 2) * 68 + r] = v.z;
        WT[(c4 * 4 + 3) * 68 + r] = v.w;
    }
    __syncthreads();
    int ty = tid >> 4, tx = tid & 15;
    float acc[4][4] = {};
    for (int k = 0; k < 128; k += 4) {
        float4 a4[4], bb[4];
        #pragma unroll
        for (int i = 0; i < 4; ++i) a4[i] = *(const float4*)&AX[(ty * 4 + i) * 128 + k];
        #pragma unroll
        for (int j = 0; j < 4; ++j) bb[j] = *(const float4*)&WT[(k + j) * 68 + tx * 4];
        #pragma unroll
        for (int i = 0; i < 4; ++i) {
            float ax = a4[i].x, ay = a4[i].y, az = a4[i].z, aw = a4[i].w;
            acc[i][0] += ax * bb[0].x + ay * bb[1].x + az * bb[2].x + aw * bb[3].x;
            acc[i][1] += ax * bb[0].y + ay * bb[1].y + az * bb[2].y + aw * bb[3].y;
            acc[i][2] += ax * bb[0].z + ay * bb[1].z + az * bb[2].z + aw * bb[3].z;
            acc[i][3] += ax * bb[0].w + ay * bb[1].w + az * bb[2].w + aw * bb[3].w;
        }
    }
    bool isq = (o0 < 1024);
    int head = (o0 & 1023) >> 7;
    int d0 = (o0 & 127) + tx * 4;
    __hip_bfloat16* basep = isq ? q_bf : kt_bf;
    #pragma unroll
    for (int i = 0; i < 4; ++i) {
        int t = t0 + ty * 4 + i;
        int b = t >> 10, pos = t & 1023;
        size_t row;
        if (isq) row = ((size_t)(b * 8 + head) * 1024 + pos);
        else { int I = pos >> 5, J = pos & 31; row = ((size_t)(b * 8 + head) * 1024 + (J * 32 + I)); }
        __hip_bfloat16* dst = basep + row * 128 + d0;
        *(__hip_bfloat162*)(dst + 0) = __float22bfloat162_rn(make_float2(acc[i][0], acc[i][1]));
        *(__hip_bfloat162*)(dst + 2) = __float22bfloat162_rn(make_float2(acc[i][2], acc[i][3]));
    }
}

// ---------------- K3: relative-position biases ----------------
// rbias[(bh*1024 + I*32+J)*32 + K] = sum_{d<64} q[d]   * row_emb[K-I+31][d]
// cbias[(bh*1024 + I*32+J)*32 + L] = sum_{d<64} q[64+d]* col_emb[L-J+31][d]
__global__ __launch_bounds__(256) void k_bias(const __hip_bfloat16* __restrict__ q_bf,
    const float* __restrict__ row_emb, const float* __restrict__ col_emb,
    float* __restrict__ rbias, float* __restrict__ cbias)
{
    int blk = blockIdx.x;          // (bh)*32 + I
    int I  = blk & 31;
    int bh = blk >> 5;
    __shared__ __align__(16) float qs[32 * 128];
    __shared__ __align__(16) float re_s[32 * 64];
    __shared__ __align__(16) float ce_s[63 * 64];
    int tid = threadIdx.x;
    #pragma unroll
    for (int it = 0; it < 2; ++it) {
        int s = tid + it * 256;        // 512: 32 rows x 16 (8 bf16)
        int r = s >> 4, c8 = s & 15;
        uint4 u = *(const uint4*)(q_bf + ((size_t)bh * 1024 + I * 32 + r) * 128 + c8 * 8);
        float f[8]; bf8_to_f(u, f);
        #pragma unroll
        for (int j = 0; j < 8; ++j) qs[r * 128 + c8 * 8 + j] = f[j];
    }
    #pragma unroll
    for (int it = 0; it < 2; ++it) {
        int s = tid + it * 256;        // 512: 32 K-rows x 16 f4
        int K = s >> 4, c4 = s & 15;
        *(float4*)&re_s[K * 64 + c4 * 4] =
            *(const float4*)(row_emb + (size_t)(K - I + 31) * 64 + c4 * 4);
    }
    #pragma unroll
    for (int it = 0; it < 4; ++it) {
        int s = tid + it * 256;        // 1008: 63 rows x 16 f4
        if (s < 1008) {
            int r = s >> 4, c4 = s & 15;
            *(float4*)&ce_s[r * 64 + c4 * 4] =
                *(const float4*)(col_emb + (size_t)r * 64 + c4 * 4);
        }
    }
    __syncthreads();
    #pragma unroll
    for (int it = 0; it < 8; ++it) {
        int wi = tid + it * 256;
        float sum = 0.f;
        if (wi < 1024) {
            int J = wi >> 5, K = wi & 31;
            const float* qp = &qs[J * 128];
            const float* ep = &re_s[K * 64];
            #pragma unroll 8
            for (int d = 0; d < 64; ++d) sum += qp[d] * ep[d];
            rbias[((size_t)bh * 1024 + I * 32 + J) * 32 + K] = sum;
        } else {
            int J = (wi - 1024) >> 5, L = (wi - 1024) & 31;
            const float* qp = &qs[J * 128 + 64];
            const float* ep = &ce_s[(L - J + 31) * 64];
            #pragma unroll 8
            for (int d = 0; d < 64; ++d) sum += qp[d] * ep[d];
            cbias[((size_t)bh * 1024 + I * 32 + J) * 32 + L] = sum;
        }
    }
}

// ---------------- K4: scores -> raw logits into probs region ----------------
// probs[b,J,I,head, kk]  (kk = L*32+K), value = (q.kt + rb[K] + cb[L]) / sqrt(128)
__global__ __launch_bounds__(256) void k_scores(const __hip_bfloat16* __restrict__ q_bf,
    const __hip_bfloat16* __restrict__ kt_bf, const float* __restrict__ rbias,
    const float* __restrict__ cbias, float* __restrict__ probs)
{
    int kt = blockIdx.x;   // 0..15
    int qt = blockIdx.y;   // 0..15
    int bh = blockIdx.z;   // 0..63
    int q0 = qt * 64, k0 = kt * 64;
    __shared__ __align__(16) float Aq[64 * 128];   // [q][k]
    __shared__ __align__(16) float BkT[128 * 68];  // [k][kk]
    __shared__ __align__(16) float rb[64 * 32];
    __shared__ float cb[64 * 2];
    int tid = threadIdx.x;
    #pragma unroll
    for (int it = 0; it < 4; ++it) {
        int s = tid + it * 256;        // 1024: 64 rows x 16 (8 bf16)
        int r = s >> 4, c8 = s & 15;
        uint4 u = *(const uint4*)(q_bf + ((size_t)bh * 1024 + q0 + r) * 128 + c8 * 8);
        float f[8]; bf8_to_f(u, f);
        #pragma unroll
        for (int j = 0; j < 8; ++j) Aq[r * 128 + c8 * 8 + j] = f[j];
    }
    #pragma unroll
    for (int it = 0; it < 4; ++it) {
        int s = tid + it * 256;
        int r = s >> 4, c8 = s & 15;   // r = kk-row, c8*8 = k
        uint4 u = *(const uint4*)(kt_bf + ((size_t)bh * 1024 + k0 + r) * 128 + c8 * 8);
        float f[8]; bf8_to_f(u, f);
        #pragma unroll
        for (int j = 0; j < 8; ++j) BkT[(c8 * 8 + j) * 68 + r] = f[j];
    }
    #pragma unroll
    for (int it = 0; it < 2; ++it) {
        int s = tid + it * 256;        // 512: 64 rows x 8 f4
        int r = s >> 3, c4 = s & 7;
        *(float4*)&rb[r * 32 + c4 * 4] =
            *(const float4*)(rbias + ((size_t)bh * 1024 + q0 + r) * 32 + c4 * 4);
    }
    if (tid < 128) {
        int r = tid >> 1, j = tid & 1;
        cb[r * 2 + j] = cbias[((size_t)bh * 1024 + q0 + r) * 32 + (k0 >> 5) + j];
    }
    __syncthreads();
    int ty = tid >> 4, tx = tid & 15;
    float acc[4][4] = {};
    for (int k = 0; k < 128; k += 4) {
        float4 a4[4], bb[4];
        #pragma unroll
        for (int i = 0; i < 4; ++i) a4[i] = *(const float4*)&Aq[(ty * 4 + i) * 128 + k];
        #pragma unroll
        for (int j = 0; j < 4; ++j) bb[j] = *(const float4*)&BkT[(k + j) * 68 + tx * 4];
        #pragma unroll
        for (int i = 0; i < 4; ++i) {
            float ax = a4[i].x, ay = a4[i].y, az = a4[i].z, aw = a4[i].w;
            acc[i][0] += ax * bb[0].x + ay * bb[1].x + az * bb[2].x + aw * bb[3].x;
            acc[i][1] += ax * bb[0].y + ay * bb[1].y + az * bb[2].y + aw * bb[3].y;
            acc[i][2] += ax * bb[0].z + ay * bb[1].z + az * bb[2].z + aw * bb[3].z;
            acc[i][3] += ax * bb[0].w + ay * bb[1].w + az * bb[2].w + aw * bb[3].w;
        }
    }
    int b = bh >> 3, head = bh & 7;
    #pragma unroll
    for (int i = 0; i < 4; ++i) {
        int qloc = ty * 4 + i;
        int q = q0 + qloc;
        int I = q >> 5, J = q & 31;
        float o[4];
        #pragma unroll
        for (int m = 0; m < 4; ++m) {
            int kkloc = tx * 4 + m;
            int K = kkloc & 31;
            int lj = kkloc >> 5;
            o[m] = (acc[i][m] + rb[qloc * 32 + K] + cb[qloc * 2 + lj]) * INV_SQRT_D;
        }
        float* dst = probs + ((((size_t)(b * 32 + J) * 32 + I) * 8 + head) << 10) + k0 + tx * 4;
        *(float4*)dst = make_float4(o[0], o[1], o[2], o[3]);
    }
}

// ---------------- K5: in-place softmax over 1024 contiguous ----------------
__global__ __launch_bounds__(256) void k_softmax(float* __restrict__ probs)
{
    size_t base = (size_t)blockIdx.x << 10;
    int tid = threadIdx.x;
    float4 v = *(float4*)(probs + base + tid * 4);
    float m = fmaxf(fmaxf(v.x, v.y), fmaxf(v.z, v.w));
    #pragma unroll
    for (int off = 1; off < 64; off <<= 1) m = fmaxf(m, __shfl_xor(m, off));
    __shared__ float redm[4], reds[4];
    int wid = tid >> 6, lane = tid & 63;
    if (lane == 0) redm[wid] = m;
    __syncthreads();
    m = fmaxf(fmaxf(redm[0], redm[1]), fmaxf(redm[2], redm[3]));
    v.x = __expf(v.x - m); v.y = __expf(v.y - m);
    v.z = __expf(v.z - m); v.w = __expf(v.w - m);
    float s = v.x + v.y + v.z + v.w;
    #pragma unroll
    for (int off = 1; off < 64; off <<= 1) s += __shfl_xor(s, off);
    if (lane == 0) reds[wid] = s;
    __syncthreads();
    s = reds[0] + reds[1] + reds[2] + reds[3];
    float inv = 1.0f / s;
    v.x *= inv; v.y *= inv; v.z *= inv; v.w *= inv;
    *(float4*)(probs + base + tid * 4) = v;
}

// ---------------- K6: context = probs @ x ----------------
// ctx_bf[(b*32+J)*32+I][head*128+d] = sum_kk probs[b,J,I,head,kk] * xf[b*1024+kk][d]
__global__ __launch_bounds__(256) void k_ctx(const float* __restrict__ probs,
    const float* __restrict__ xf, __hip_bfloat16* __restrict__ ctx_bf)
{
    int qt = blockIdx.x, bh = blockIdx.y;
    int b = bh >> 3, head = bh & 7;
    int q0 = qt * 64;
    __shared__ __align__(16) float AP[64 * 68];    // [q][kk]
    __shared__ __align__(16) float BX[64 * 128];   // [kk][d]
    int tid = threadIdx.x;
    int ty = tid >> 4, tx = tid & 15;
    float acc[4][8] = {};
    for (int kk0 = 0; kk0 < 1024; kk0 += 64) {
        __syncthreads();
        #pragma unroll
        for (int it = 0; it < 4; ++it) {
            int s = tid + it * 256;     // 1024: 64 q x 16 f4
            int r = s >> 4, c4 = s & 15;
            int q = q0 + r;
            int I = q >> 5, J = q & 31;
            const float* src = probs + ((((size_t)(b * 32 + J) * 32 + I) * 8 + head) << 10)
                                     + kk0 + c4 * 4;
            *(float4*)&AP[r * 68 + c4 * 4] = *(const float4*)src;
        }
        #pragma unroll
        for (int it = 0; it < 8; ++it) {
            int s = tid + it * 256;     // 2048: 64 kk x 32 f4
            int r = s >> 5, c4 = s & 31;
            *(float4*)&BX[r * 128 + c4 * 4] =
                *(const float4*)(xf + ((size_t)b * 1024 + kk0 + r) * 128 + c4 * 4);
        }
        __syncthreads();
        for (int kk = 0; kk < 64; kk += 4) {
            float4 a4[4];
            #pragma unroll
            for (int i = 0; i < 4; ++i) a4[i] = *(const float4*)&AP[(ty * 4 + i) * 68 + kk];
            #pragma unroll
            for (int j = 0; j < 4; ++j) {
                float4 b0 = *(const float4*)&BX[(kk + j) * 128 + tx * 8];
                float4 b1 = *(const float4*)&BX[(kk + j) * 128 + tx * 8 + 4];
                #pragma unroll
                for (int i = 0; i < 4; ++i) {
                    float av = (j == 0) ? a4[i].x : (j == 1) ? a4[i].y : (j == 2) ? a4[i].z : a4[i].w;
                    acc[i][0] += av * b0.x; acc[i][1] += av * b0.y;
                    acc[i][2] += av * b0.z; acc[i][3] += av * b0.w;
                    acc[i][4] += av * b1.x; acc[i][5] += av * b1.y;
                    acc[i][6] += av * b1.z; acc[i][7] += av * b1.w;
                }
            }
        }
    }
    #pragma unroll
    for (int i = 0; i < 4; ++i) {
        int q = q0 + ty * 4 + i;
        int I = q >> 5, J = q & 31;
        __hip_bfloat16* dst = ctx_bf + ((size_t)(b * 32 + J) * 32 + I) * 1024 + head * 128 + tx * 8;
        #pragma unroll
        for (int p = 0; p < 4; ++p) {
            *(__hip_bfloat162*)(dst + 2 * p) =
                __float22bfloat162_rn(make_float2(acc[i][2 * p], acc[i][2 * p + 1]));
        }
    }
}

// ---------------- K7: output = ctx @ Wv^T + bv + x ----------------
__global__ __launch_bounds__(256) void k_out(const __hip_bfloat16* __restrict__ ctx_bf,
    const float* __restrict__ Wv, const float* __restrict__ bv,
    const float* __restrict__ xf, float* __restrict__ out)
{
    int t0 = blockIdx.x * 64;
    int o0 = blockIdx.y * 64;
    __shared__ __align__(16) float AT[64 * 132];   // [t][c]  (c-tile of 64, padded row 132)
    __shared__ __align__(16) float WT[64 * 68];    // [c][o]
    int tid = threadIdx.x;
    int ty = tid >> 4, tx = tid & 15;
    float acc[4][4] = {};
    for (int c0 = 0; c0 < 1024; c0 += 64) {
        __syncthreads();
        #pragma unroll
        for (int it = 0; it < 2; ++it) {
            int s = tid + it * 256;     // 512: 64 t x 8 (8 bf16)
            int r = s >> 3, c8 = s & 7;
            uint4 u = *(const uint4*)(ctx_bf + (size_t)(t0 + r) * 1024 + c0 + c8 * 8);
            float f[8]; bf8_to_f(u, f);
            *(float4*)&AT[r * 132 + c8 * 8 + 0] = make_float4(f[0], f[1], f[2], f[3]);
            *(float4*)&AT[r * 132 + c8 * 8 + 4] = make_float4(f[4], f[5], f[6], f[7]);
        }
        #pragma unroll
        for (int it = 0; it < 4; ++it) {
            int s = tid + it * 256;     // 1024: 64 o x 16 f4
            int r = s >> 4, c4 = s & 15;
            float4 v = *(const float4*)(Wv + (size_t)(o0 + r) * 1024 + c0 + c4 * 4);
            WT[(c4 * 4 + 0) * 68 + r] = v.x;
            WT[(c4 * 4 + 1) * 68 + r] = v.y;
            WT[(c4 * 4 + 2) * 68 + r] = v.z;
            WT[(c4 * 4 + 3) * 68 + r] = v.w;
        }
        __syncthreads();
        for (int c = 0; c < 64; c += 4) {
            float4 a4[4], bb[4];
            #pragma unroll
            for (int i = 0; i < 4; ++i) a4[i] = *(const float4*)&AT[(ty * 4 + i) * 132 + c];
            #pragma unroll
            for (int j = 0; j < 4; ++j) bb[j] = *(const float4*)&WT[(c + j) * 68 + tx * 4];
            #pragma unroll
            for (int i = 0; i < 4; ++i) {
                float ax = a4[i].x, ay = a4[i].y, az = a4[i].z, aw = a4[i].w;
                acc[i][0] += ax * bb[0].x + ay * bb[1].x + az * bb[2].x + aw * bb[3].x;
                acc[i][1] += ax * bb[0].y + ay * bb[1].y + az * bb[2].y + aw * bb[3].y;
                acc[i][2] += ax * bb[0].z + ay * bb[1].z + az * bb[2].z + aw * bb[3].z;
                acc[i][3] += ax * bb[0].w + ay * bb[1].w + az * bb[2].w + aw * bb[3].w;
            }
        }
    }
    #pragma unroll
    for (int i = 0; i < 4; ++i) {
        int t = t0 + ty * 4 + i;
        float4 r  = *(const float4*)(xf + (size_t)t * 128 + o0 + tx * 4);
        float4 bvv = *(const float4*)(bv + o0 + tx * 4);
        float4 o;
        o.x = acc[i][0] + bvv.x + r.x;
        o.y = acc[i][1] + bvv.y + r.y;
        o.z = acc[i][2] + bvv.z + r.z;
        o.w = acc[i][3] + bvv.w + r.w;
        *(float4*)(out + (size_t)t * 128 + o0 + tx * 4) = o;
    }
}

extern "C" void kernel_launch(void* const* d_in, const int* in_sizes, int n_in,
                              void* d_out, int out_size, void* d_ws, size_t ws_size,
                              hipStream_t stream) {
    (void)in_sizes; (void)n_in; (void)out_size; (void)ws_size;
    const float* hs      = (const float*)d_in[0];
    const float* row_emb = (const float*)d_in[1];
    const float* col_emb = (const float*)d_in[2];
    const float* Wq      = (const float*)d_in[3];
    const float* Wk      = (const float*)d_in[4];
    const float* Wv      = (const float*)d_in[5];
    const float* bv      = (const float*)d_in[6];
    const float* ln_g    = (const float*)d_in[7];
    const float* ln_b    = (const float*)d_in[8];

    float* out   = (float*)d_out;
    float* probs = out + 1048576;        // output0 = 8*32*32*128

    char* ws = (char*)d_ws;              // total 68 MB
    float*          xf     = (float*)(ws);                         //  4 MB fp32 LN(x)
    __hip_bfloat16* q_bf   = (__hip_bfloat16*)(ws + 4194304);      // 16 MB
    __hip_bfloat16* kt_bf  = (__hip_bfloat16*)(ws + 20971520);     // 16 MB
    float*          rbias  = (float*)(ws + 37748736);              //  8 MB
    float*          cbias  = (float*)(ws + 46137344);              //  8 MB
    __hip_bfloat16* ctx_bf = (__hip_bfloat16*)(ws + 54525952);     // 16 MB

    k_ln     <<<2048, 256, 0, stream>>>(hs, ln_g, ln_b, xf);
    k_proj   <<<dim3(128, 32), 256, 0, stream>>>(xf, Wq, Wk, q_bf, kt_bf);
    k_bias   <<<2048, 256, 0, stream>>>(q_bf, row_emb, col_emb, rbias, cbias);
    k_scores <<<dim3(16, 16, 64), 256, 0, stream>>>(q_bf, kt_bf, rbias, cbias, probs);
    k_softmax<<<65536, 256, 0, stream>>>(probs);
    k_ctx    <<<dim3(16, 64), 256, 0, stream>>>(probs, xf, ctx_bf);
    k_out    <<<dim3(128, 2), 256, 0, stream>>>(ctx_bf, Wv, bv, xf, out);
}

// Round 2
// 449.717 us; speedup vs baseline: 2.1226x; 2.1226x over previous
//
#include <hip/hip_runtime.h>
#include <hip/hip_bf16.h>

#define HEADS 8
#define D 128
#define INV_SQRT_D 0.08838834764831845f

typedef unsigned short u16;
typedef __attribute__((ext_vector_type(8))) short short8;
typedef __attribute__((ext_vector_type(4))) float f32x4;

static __device__ inline float sbf2f(short s) {
    return __uint_as_float(((unsigned int)(unsigned short)s) << 16);
}
static __device__ inline u16 f2bf(float f) {
    unsigned int u = __float_as_uint(f);
    return (u16)((u + 0x7FFFu + ((u >> 16) & 1u)) >> 16);
}
static __device__ inline float bf2f(unsigned int u) {
    return __uint_as_float(u << 16);
}
__device__ inline void bf8_to_f(const uint4 u, float* o) {
    o[0] = bf2f(u.x & 0xffffu); o[1] = bf2f(u.x >> 16);
    o[2] = bf2f(u.y & 0xffffu); o[3] = bf2f(u.y >> 16);
    o[4] = bf2f(u.z & 0xffffu); o[5] = bf2f(u.z >> 16);
    o[6] = bf2f(u.w & 0xffffu); o[7] = bf2f(u.w >> 16);
}
static __device__ inline f32x4 mfma16(short8 a, short8 b, f32x4 c) {
    return __builtin_amdgcn_mfma_f32_16x16x32_bf16(a, b, c, 0, 0, 0);
}

// ---------------- K1: LayerNorm (f32 + bf16 outputs) ----------------
__global__ __launch_bounds__(256) void k_ln(const float* __restrict__ hs,
    const float* __restrict__ g, const float* __restrict__ b,
    float* __restrict__ xf, u16* __restrict__ xbf)
{
    int row  = blockIdx.x * 4 + (threadIdx.x >> 6);
    int lane = threadIdx.x & 63;
    const float* p = hs + (size_t)row * D + lane * 2;
    float2 v = *(const float2*)p;
    float s  = v.x + v.y;
    float s2 = v.x * v.x + v.y * v.y;
    #pragma unroll
    for (int off = 1; off < 64; off <<= 1) {
        s  += __shfl_xor(s, off);
        s2 += __shfl_xor(s2, off);
    }
    float mu  = s * 0.0078125f;
    float var = s2 * 0.0078125f - mu * mu;
    float inv = rsqrtf(var + 1e-5f);
    float2 o;
    o.x = (v.x - mu) * inv * g[lane * 2 + 0] + b[lane * 2 + 0];
    o.y = (v.y - mu) * inv * g[lane * 2 + 1] + b[lane * 2 + 1];
    *(float2*)(xf + (size_t)row * D + lane * 2) = o;
    unsigned int pk = ((unsigned int)f2bf(o.y) << 16) | f2bf(o.x);
    *(unsigned int*)(xbf + (size_t)row * D + lane * 2) = pk;
}

// ---------------- K1b: transpose x -> xt[b][d][pos] bf16 ----------------
__global__ __launch_bounds__(256) void k_xt(const float* __restrict__ xf,
    u16* __restrict__ xt)
{
    __shared__ __align__(16) u16 tl[128][136];   // pitch 272B (16B-mult, bank-rotating)
    int b = blockIdx.x, ch = blockIdx.y;
    int tid = threadIdx.x;
    const float* src = xf + ((size_t)b * 1024 + ch * 128) * 128;
    #pragma unroll
    for (int it = 0; it < 16; ++it) {
        int s = tid + it * 256;          // 4096 float4: 128 pos x 32
        int p = s >> 5, d4 = (s & 31) * 4;
        f32x4 v = *(const f32x4*)(src + (size_t)p * 128 + d4);
        tl[d4 + 0][p] = f2bf(v[0]);
        tl[d4 + 1][p] = f2bf(v[1]);
        tl[d4 + 2][p] = f2bf(v[2]);
        tl[d4 + 3][p] = f2bf(v[3]);
    }
    __syncthreads();
    u16* dst = xt + (size_t)b * 131072 + ch * 128;
    #pragma unroll
    for (int i = 0; i < 8; ++i) {
        int d = (tid >> 4) + i * 16, c8 = (tid & 15) * 8;
        *(uint4*)(dst + (size_t)d * 1024 + c8) = *(const uint4*)&tl[d][c8];
    }
}

// ---------------- K2: Q/K projection (MFMA bf16) ----------------
// q_bf[(b*8+head)*1024 + pos][d],  kt_bf[(b*8+head)*1024 + (J*32+I)][d]
__global__ __launch_bounds__(256) void k_proj(const u16* __restrict__ xbf,
    const float* __restrict__ Wq, const float* __restrict__ Wk,
    u16* __restrict__ q_bf, u16* __restrict__ kt_bf)
{
    int tid = threadIdx.x;
    int w = tid >> 6, l = tid & 63, h = l >> 4, ln = l & 15;
    int t0 = blockIdx.x * 64 + w * 16;
    int o0 = blockIdx.y * 64;
    short8 a[4];
    #pragma unroll
    for (int s = 0; s < 4; ++s)
        a[s] = *(const short8*)(xbf + (size_t)(t0 + ln) * 128 + s * 32 + h * 8);
    f32x4 acc[4];
    #pragma unroll
    for (int n = 0; n < 4; ++n) acc[n] = f32x4{0.f, 0.f, 0.f, 0.f};
    #pragma unroll
    for (int n = 0; n < 4; ++n) {
        int o = o0 + n * 16 + ln;
        const float* wsrc = (o < 1024) ? (Wq + (size_t)o * 128)
                                       : (Wk + (size_t)(o - 1024) * 128);
        #pragma unroll
        for (int s = 0; s < 4; ++s) {
            f32x4 w0 = *(const f32x4*)(wsrc + s * 32 + h * 8);
            f32x4 w1 = *(const f32x4*)(wsrc + s * 32 + h * 8 + 4);
            short8 bf;
            bf[0] = (short)f2bf(w0[0]); bf[1] = (short)f2bf(w0[1]);
            bf[2] = (short)f2bf(w0[2]); bf[3] = (short)f2bf(w0[3]);
            bf[4] = (short)f2bf(w1[0]); bf[5] = (short)f2bf(w1[1]);
            bf[6] = (short)f2bf(w1[2]); bf[7] = (short)f2bf(w1[3]);
            acc[n] = mfma16(a[s], bf, acc[n]);
        }
    }
    bool isq = (o0 < 1024);
    int head = (o0 & 1023) >> 7;
    int od_base = (o0 & 127);
    u16* basep = isq ? q_bf : kt_bf;
    #pragma unroll
    for (int n = 0; n < 4; ++n) {
        int d0 = od_base + n * 16 + ln;
        #pragma unroll
        for (int r = 0; r < 4; ++r) {
            int t = t0 + h * 4 + r;
            int b = t >> 10, pos = t & 1023;
            size_t row;
            if (isq) row = (size_t)(b * 8 + head) * 1024 + pos;
            else { int I = pos >> 5, J = pos & 31; row = (size_t)(b * 8 + head) * 1024 + (J * 32 + I); }
            basep[row * 128 + d0] = f2bf(acc[n][r]);
        }
    }
}

// ---------------- K3: relative-position biases (unchanged) ----------------
__global__ __launch_bounds__(256) void k_bias(const __hip_bfloat16* __restrict__ q_bf,
    const float* __restrict__ row_emb, const float* __restrict__ col_emb,
    float* __restrict__ rbias, float* __restrict__ cbias)
{
    int blk = blockIdx.x;
    int I  = blk & 31;
    int bh = blk >> 5;
    __shared__ __align__(16) float qs[32 * 128];
    __shared__ __align__(16) float re_s[32 * 64];
    __shared__ __align__(16) float ce_s[63 * 64];
    int tid = threadIdx.x;
    #pragma unroll
    for (int it = 0; it < 2; ++it) {
        int s = tid + it * 256;
        int r = s >> 4, c8 = s & 15;
        uint4 u = *(const uint4*)((const u16*)q_bf + ((size_t)bh * 1024 + I * 32 + r) * 128 + c8 * 8);
        float f[8]; bf8_to_f(u, f);
        #pragma unroll
        for (int j = 0; j < 8; ++j) qs[r * 128 + c8 * 8 + j] = f[j];
    }
    #pragma unroll
    for (int it = 0; it < 2; ++it) {
        int s = tid + it * 256;
        int K = s >> 4, c4 = s & 15;
        *(float4*)&re_s[K * 64 + c4 * 4] =
            *(const float4*)(row_emb + (size_t)(K - I + 31) * 64 + c4 * 4);
    }
    #pragma unroll
    for (int it = 0; it < 4; ++it) {
        int s = tid + it * 256;
        if (s < 1008) {
            int r = s >> 4, c4 = s & 15;
            *(float4*)&ce_s[r * 64 + c4 * 4] =
                *(const float4*)(col_emb + (size_t)r * 64 + c4 * 4);
        }
    }
    __syncthreads();
    #pragma unroll
    for (int it = 0; it < 8; ++it) {
        int wi = tid + it * 256;
        float sum = 0.f;
        if (wi < 1024) {
            int J = wi >> 5, K = wi & 31;
            const float* qp = &qs[J * 128];
            const float* ep = &re_s[K * 64];
            #pragma unroll 8
            for (int d = 0; d < 64; ++d) sum += qp[d] * ep[d];
            rbias[((size_t)bh * 1024 + I * 32 + J) * 32 + K] = sum;
        } else {
            int J = (wi - 1024) >> 5, L = (wi - 1024) & 31;
            const float* qp = &qs[J * 128 + 64];
            const float* ep = &ce_s[(L - J + 31) * 64];
            #pragma unroll 8
            for (int d = 0; d < 64; ++d) sum += qp[d] * ep[d];
            cbias[((size_t)bh * 1024 + I * 32 + J) * 32 + L] = sum;
        }
    }
}

// ---------------- K4: fused scores+softmax+PV ----------------
// block: (qt, bh); 32 q-rows (I=qt fixed, J=0..31), 4 waves x 256-kk spans.
__global__ __launch_bounds__(256, 2) void k_attn(const u16* __restrict__ q_bf,
    const u16* __restrict__ kt_bf, const u16* __restrict__ xt_bf,
    const float* __restrict__ rbias, const float* __restrict__ cbias,
    float* __restrict__ probs, u16* __restrict__ ctx_bf)
{
    __shared__ __align__(16) u16 P[32 * 1024];          // 64 KB, XOR-swizzled
    __shared__ __align__(16) float rb_s[32 * 32];
    __shared__ __align__(16) float cb_s[32 * 32];
    __shared__ float wred[2][128];                       // [max|sum][wave*32+J]
    int tid = threadIdx.x;
    int w = tid >> 6, l = tid & 63, h = l >> 4, ln = l & 15;
    int qt = blockIdx.x, bh = blockIdx.y;
    int b = bh >> 3, head = bh & 7;
    int q0 = qt * 32;
    // stage rb/cb
    {
        int J = tid >> 3, c4 = (tid & 7) * 4;
        *(f32x4*)&rb_s[J * 32 + c4] = *(const f32x4*)(rbias + ((size_t)bh * 1024 + q0 + J) * 32 + c4);
        *(f32x4*)&cb_s[J * 32 + c4] = *(const f32x4*)(cbias + ((size_t)bh * 1024 + q0 + J) * 32 + c4);
    }
    // Q fragments (held)
    short8 qa[2][4];
    const u16* qbase = q_bf + ((size_t)bh * 1024 + q0) * 128;
    #pragma unroll
    for (int m = 0; m < 2; ++m)
        #pragma unroll
        for (int s = 0; s < 4; ++s)
            qa[m][s] = *(const short8*)(qbase + (size_t)(m * 16 + ln) * 128 + s * 32 + h * 8);
    // phase 1: S = Q K^T over this wave's 256-kk span
    f32x4 acc[2][16];
    #pragma unroll
    for (int m = 0; m < 2; ++m)
        #pragma unroll
        for (int t = 0; t < 16; ++t) acc[m][t] = f32x4{0.f, 0.f, 0.f, 0.f};
    int kk0 = w * 256;
    const u16* kbase = kt_bf + ((size_t)bh * 1024 + kk0) * 128;
    #pragma unroll
    for (int t = 0; t < 16; ++t) {
        #pragma unroll
        for (int s = 0; s < 4; ++s) {
            short8 kf = *(const short8*)(kbase + (size_t)(t * 16 + ln) * 128 + s * 32 + h * 8);
            acc[0][t] = mfma16(qa[0][s], kf, acc[0][t]);
            acc[1][t] = mfma16(qa[1][s], kf, acc[1][t]);
        }
    }
    __syncthreads();          // rb/cb staged
    // bias + scale + per-wave rowmax
    #pragma unroll
    for (int m = 0; m < 2; ++m) {
        #pragma unroll
        for (int r = 0; r < 4; ++r) {
            int J = m * 16 + h * 4 + r;
            float rb0 = rb_s[J * 32 + ln];
            float rb1 = rb_s[J * 32 + 16 + ln];
            float mx = -1e30f;
            #pragma unroll
            for (int t = 0; t < 16; ++t) {
                float cbv = cb_s[J * 32 + (kk0 >> 5) + (t >> 1)];
                float v = (acc[m][t][r] + ((t & 1) ? rb1 : rb0) + cbv) * INV_SQRT_D;
                acc[m][t][r] = v;
                mx = fmaxf(mx, v);
            }
            mx = fmaxf(mx, __shfl_xor(mx, 1));
            mx = fmaxf(mx, __shfl_xor(mx, 2));
            mx = fmaxf(mx, __shfl_xor(mx, 4));
            mx = fmaxf(mx, __shfl_xor(mx, 8));
            if (ln == 0) wred[0][w * 32 + J] = mx;
        }
    }
    __syncthreads();
    // global max, exp, sums, write P~ (bf16, swizzled)
    #pragma unroll
    for (int m = 0; m < 2; ++m) {
        #pragma unroll
        for (int r = 0; r < 4; ++r) {
            int J = m * 16 + h * 4 + r;
            float M = fmaxf(fmaxf(wred[0][J], wred[0][32 + J]),
                            fmaxf(wred[0][64 + J], wred[0][96 + J]));
            float sum = 0.f;
            #pragma unroll
            for (int t = 0; t < 16; ++t) {
                float p = __expf(acc[m][t][r] - M);
                acc[m][t][r] = p;
                sum += p;
            }
            sum += __shfl_xor(sum, 1);
            sum += __shfl_xor(sum, 2);
            sum += __shfl_xor(sum, 4);
            sum += __shfl_xor(sum, 8);
            if (ln == 0) wred[1][w * 32 + J] = sum;
            #pragma unroll
            for (int t = 0; t < 16; ++t) {
                int kk = kk0 + t * 16 + ln;
                int byteoff = J * 2048 + ((kk * 2) ^ ((J & 7) << 4));
                *(u16*)((char*)P + byteoff) = f2bf(acc[m][t][r]);
            }
        }
    }
    __syncthreads();
    // phase 3: ctx = P~ @ X  (wave w -> d-span w*32)
    f32x4 cacc[2][2];
    #pragma unroll
    for (int m = 0; m < 2; ++m)
        #pragma unroll
        for (int n = 0; n < 2; ++n) cacc[m][n] = f32x4{0.f, 0.f, 0.f, 0.f};
    int d0 = w * 32;
    const u16* xb = xt_bf + (size_t)b * 131072;
    #pragma unroll 4
    for (int ks = 0; ks < 32; ++ks) {
        short8 pa[2];
        #pragma unroll
        for (int m = 0; m < 2; ++m) {
            int J = m * 16 + ln;
            int byteoff = J * 2048 + (((ks * 32 + h * 8) * 2) ^ ((J & 7) << 4));
            pa[m] = *(const short8*)((const char*)P + byteoff);
        }
        #pragma unroll
        for (int n = 0; n < 2; ++n) {
            short8 xf8 = *(const short8*)(xb + (size_t)(d0 + n * 16 + ln) * 1024 + ks * 32 + h * 8);
            cacc[0][n] = mfma16(pa[0], xf8, cacc[0][n]);
            cacc[1][n] = mfma16(pa[1], xf8, cacc[1][n]);
        }
    }
    // ctx epilogue
    #pragma unroll
    for (int m = 0; m < 2; ++m) {
        #pragma unroll
        for (int r = 0; r < 4; ++r) {
            int J = m * 16 + h * 4 + r;
            float lsum = wred[1][J] + wred[1][32 + J] + wred[1][64 + J] + wred[1][96 + J];
            float inv = 1.0f / lsum;
            u16* dst = ctx_bf + ((size_t)(b * 32 + J) * 32 + qt) * 1024 + head * 128 + d0;
            dst[ln]      = f2bf(cacc[m][0][r] * inv);
            dst[16 + ln] = f2bf(cacc[m][1][r] * inv);
        }
    }
    // probs output (normalized), coalesced from LDS
    {
        int J = tid >> 3;
        float lsum = wred[1][J] + wred[1][32 + J] + wred[1][64 + J] + wred[1][96 + J];
        float inv = 1.0f / lsum;
        float* prow = probs + ((((size_t)(b * 32 + J) * 32 + qt) * 8 + head) << 10);
        #pragma unroll
        for (int i = 0; i < 16; ++i) {
            int kk = i * 64 + (tid & 7) * 8;
            int byteoff = J * 2048 + ((kk * 2) ^ ((J & 7) << 4));
            short8 pv = *(const short8*)((const char*)P + byteoff);
            float4 o0, o1;
            o0.x = sbf2f(pv[0]) * inv; o0.y = sbf2f(pv[1]) * inv;
            o0.z = sbf2f(pv[2]) * inv; o0.w = sbf2f(pv[3]) * inv;
            o1.x = sbf2f(pv[4]) * inv; o1.y = sbf2f(pv[5]) * inv;
            o1.z = sbf2f(pv[6]) * inv; o1.w = sbf2f(pv[7]) * inv;
            *(float4*)(prow + kk)     = o0;
            *(float4*)(prow + kk + 4) = o1;
        }
    }
}

// ---------------- K7: output = ctx @ Wv^T + bv + x (unchanged) ----------------
__global__ __launch_bounds__(256) void k_out(const __hip_bfloat16* __restrict__ ctx_bf,
    const float* __restrict__ Wv, const float* __restrict__ bv,
    const float* __restrict__ xf, float* __restrict__ out)
{
    int t0 = blockIdx.x * 64;
    int o0 = blockIdx.y * 64;
    __shared__ __align__(16) float AT[64 * 132];
    __shared__ __align__(16) float WT[64 * 68];
    int tid = threadIdx.x;
    int ty = tid >> 4, tx = tid & 15;
    float acc[4][4] = {};
    for (int c0 = 0; c0 < 1024; c0 += 64) {
        __syncthreads();
        #pragma unroll
        for (int it = 0; it < 2; ++it) {
            int s = tid + it * 256;
            int r = s >> 3, c8 = s & 7;
            uint4 u = *(const uint4*)((const u16*)ctx_bf + (size_t)(t0 + r) * 1024 + c0 + c8 * 8);
            float f[8]; bf8_to_f(u, f);
            *(float4*)&AT[r * 132 + c8 * 8 + 0] = make_float4(f[0], f[1], f[2], f[3]);
            *(float4*)&AT[r * 132 + c8 * 8 + 4] = make_float4(f[4], f[5], f[6], f[7]);
        }
        #pragma unroll
        for (int it = 0; it < 4; ++it) {
            int s = tid + it * 256;
            int r = s >> 4, c4 = s & 15;
            float4 v = *(const float4*)(Wv + (size_t)(o0 + r) * 1024 + c0 + c4 * 4);
            WT[(c4 * 4 + 0) * 68 + r] = v.x;
            WT[(c4 * 4 + 1) * 68 + r] = v.y;
            WT[(c4 * 4 + 2) * 68 + r] = v.z;
            WT[(c4 * 4 + 3) * 68 + r] = v.w;
        }
        __syncthreads();
        for (int c = 0; c < 64; c += 4) {
            float4 a4[4], bb[4];
            #pragma unroll
            for (int i = 0; i < 4; ++i) a4[i] = *(const float4*)&AT[(ty * 4 + i) * 132 + c];
            #pragma unroll
            for (int j = 0; j < 4; ++j) bb[j] = *(const float4*)&WT[(c + j) * 68 + tx * 4];
            #pragma unroll
            for (int i = 0; i < 4; ++i) {
                float ax = a4[i].x, ay = a4[i].y, az = a4[i].z, aw = a4[i].w;
                acc[i][0] += ax * bb[0].x + ay * bb[1].x + az * bb[2].x + aw * bb[3].x;
                acc[i][1] += ax * bb[0].y + ay * bb[1].y + az * bb[2].y + aw * bb[3].y;
                acc[i][2] += ax * bb[0].z + ay * bb[1].z + az * bb[2].z + aw * bb[3].z;
                acc[i][3] += ax * bb[0].w + ay * bb[1].w + az * bb[2].w + aw * bb[3].w;
            }
        }
    }
    #pragma unroll
    for (int i = 0; i < 4; ++i) {
        int t = t0 + ty * 4 + i;
        float4 r  = *(const float4*)(xf + (size_t)t * 128 + o0 + tx * 4);
        float4 bvv = *(const float4*)(bv + o0 + tx * 4);
        float4 o;
        o.x = acc[i][0] + bvv.x + r.x;
        o.y = acc[i][1] + bvv.y + r.y;
        o.z = acc[i][2] + bvv.z + r.z;
        o.w = acc[i][3] + bvv.w + r.w;
        *(float4*)(out + (size_t)t * 128 + o0 + tx * 4) = o;
    }
}

extern "C" void kernel_launch(void* const* d_in, const int* in_sizes, int n_in,
                              void* d_out, int out_size, void* d_ws, size_t ws_size,
                              hipStream_t stream) {
    (void)in_sizes; (void)n_in; (void)out_size; (void)ws_size;
    const float* hs      = (const float*)d_in[0];
    const float* row_emb = (const float*)d_in[1];
    const float* col_emb = (const float*)d_in[2];
    const float* Wq      = (const float*)d_in[3];
    const float* Wk      = (const float*)d_in[4];
    const float* Wv      = (const float*)d_in[5];
    const float* bv      = (const float*)d_in[6];
    const float* ln_g    = (const float*)d_in[7];
    const float* ln_b    = (const float*)d_in[8];

    float* out   = (float*)d_out;
    float* probs = out + 1048576;

    char* ws = (char*)d_ws;
    float* xf    = (float*)(ws);                       //  4 MB
    u16*   xbf   = (u16*)(ws + 4194304);               //  2 MB
    u16*   q_bf  = (u16*)(ws + 6291456);               // 16 MB
    u16*   kt_bf = (u16*)(ws + 23068672);              // 16 MB
    u16*   xt    = (u16*)(ws + 39845888);              //  2 MB
    float* rbias = (float*)(ws + 41943040);            //  8 MB
    float* cbias = (float*)(ws + 50331648);            //  8 MB
    u16*   ctx   = (u16*)(ws + 58720256);              // 16 MB

    k_ln   <<<2048, 256, 0, stream>>>(hs, ln_g, ln_b, xf, xbf);
    k_xt   <<<dim3(8, 8), 256, 0, stream>>>(xf, xt);
    k_proj <<<dim3(128, 32), 256, 0, stream>>>(xbf, Wq, Wk, q_bf, kt_bf);
    k_bias <<<2048, 256, 0, stream>>>((const __hip_bfloat16*)q_bf, row_emb, col_emb, rbias, cbias);
    k_attn <<<dim3(32, 64), 256, 0, stream>>>(q_bf, kt_bf, xt, rbias, cbias, probs, ctx);
    k_out  <<<dim3(128, 2), 256, 0, stream>>>((const __hip_bfloat16*)ctx, Wv, bv, xf, out);
}